// Round 3
// baseline (737.404 us; speedup 1.0000x reference)
//
#include <hip/hip_runtime.h>
#include <hip/hip_bf16.h>

constexpr int BB = 4096;   // batch
constexpr int TT = 2048;   // time
constexpr int HH = 32;     // hidden

typedef float v2f __attribute__((ext_vector_type(2)));
typedef float v4f __attribute__((ext_vector_type(4)));

// ---------- fast math (v_exp_f32 / v_rcp_f32) ----------
__device__ __forceinline__ float fexp2(float x) { return __builtin_amdgcn_exp2f(x); }
__device__ __forceinline__ float frcp(float x)  { return __builtin_amdgcn_rcpf(x); }
__device__ __forceinline__ float fsigmoid(float x) {
    return frcp(1.0f + fexp2(x * -1.4426950408889634f));
}
__device__ __forceinline__ float ftanh(float x) {
    return 1.0f - 2.0f * frcp(1.0f + fexp2(x * 2.8853900817779268f));
}
__device__ __forceinline__ float felu(float x) {
    return x > 0.0f ? x : (fexp2(x * 1.4426950408889634f) - 1.0f);
}

// ---------- kernel 1: counting sort of batch indices by length, descending ----------
__global__ void sort_by_len_kernel(const int* __restrict__ lengths, int* __restrict__ perm) {
    __shared__ int hist[TT];     // key = TT - len  in [0, TT-1]
    __shared__ int csum[256];
    const int tid = threadIdx.x;
    for (int i = tid; i < TT; i += 256) hist[i] = 0;
    __syncthreads();
    for (int i = tid; i < BB; i += 256) atomicAdd(&hist[TT - lengths[i]], 1);
    __syncthreads();
    const int base = tid * 8;
    int loc[8];
    int s = 0;
#pragma unroll
    for (int j = 0; j < 8; ++j) { loc[j] = hist[base + j]; s += loc[j]; }
    csum[tid] = s;
    __syncthreads();
    for (int off = 1; off < 256; off <<= 1) {
        int v = (tid >= off) ? csum[tid - off] : 0;
        __syncthreads();
        csum[tid] += v;
        __syncthreads();
    }
    int run = csum[tid] - s;
#pragma unroll
    for (int j = 0; j < 8; ++j) { int t = loc[j]; hist[base + j] = run; run += t; }
    __syncthreads();
    for (int i = tid; i < BB; i += 256) {
        int pos = atomicAdd(&hist[TT - lengths[i]], 1);
        perm[pos] = i;
    }
}

// ---------- kernel 2: backward LSTM + MLP head ----------
// 1 wave per block, 1 batch element per wave. Lane owns gate rows:
//   r0 = lane        (rows 0..63   = i-gates then f-gates)
//   r1 = lane + 64   (rows 64..127 = g-gates then o-gates)
// Weights: 2 rows x 32 = 64 floats/lane, MUST live in VGPRs.
// amdgpu_waves_per_eu(2,3): max=3 stops the RA occupancy heuristic from
// rematerializing the weight loads into the loop (R2: VGPR=60 proved it
// demoted them and burned ~150 instr/step instead of ~65).
__global__ __attribute__((amdgpu_flat_work_group_size(64, 64), amdgpu_waves_per_eu(2, 3)))
void lstm_kernel(const float* __restrict__ x, const int* __restrict__ lengths,
                 const float* __restrict__ w_ih, const float* __restrict__ w_hh,
                 const float* __restrict__ b_ih, const float* __restrict__ b_hh,
                 const float* __restrict__ fc_w, const float* __restrict__ fc_b,
                 const float* __restrict__ fc2_w, const float* __restrict__ fc2_b,
                 float* __restrict__ out, const int* __restrict__ perm) {
    __shared__ __align__(16) float hbuf[64];   // only [0..31] read; [32..63] = junk pad
    __shared__ float xbuf[64];

    const int lane = threadIdx.x;       // 0..63
    const int b = perm ? perm[blockIdx.x] : blockIdx.x;
    const int L = lengths[b];

    const int r0 = lane;        // i (lane<32) / f (lane>=32) row
    const int r1 = lane + 64;   // g (lane<32) / o (lane>=32) row

    // per-lane weights in registers
    v2f w0[16], w1[16];
    {
        const v2f* p0 = reinterpret_cast<const v2f*>(w_hh + r0 * 32);
        const v2f* p1 = reinterpret_cast<const v2f*>(w_hh + r1 * 32);
#pragma unroll
        for (int q = 0; q < 16; ++q) { w0[q] = p0[q]; w1[q] = p1[q]; }
    }
    const float wi0 = w_ih[r0];
    const float wi1 = w_ih[r1];
    const float bi0 = b_ih[r0] + b_hh[r0];
    const float bi1 = b_ih[r1] + b_hh[r1];

    // unified activation for acc1: lower half -> tanh(g) = 2*sigm(2g)-1; upper -> sigm(o)
    const bool  lower = lane < 32;
    const float kmul  = lower ? -2.8853900817779268f : -1.4426950408889634f;
    const float amul  = lower ? 2.0f : 1.0f;
    const float badd  = lower ? -1.0f : 0.0f;

    v2f h2[16];
#pragma unroll
    for (int q = 0; q < 16; ++q) h2[q] = (v2f){0.0f, 0.0f};
    float c = 0.0f;
    const float* xb = x + (size_t)b * TT;

    int t = L - 1;
    while (t >= 0) {
        const int tb = t & ~63;
        __syncthreads();
        xbuf[lane] = xb[tb + lane];    // tb+63 <= 2047 always in-bounds
        __syncthreads();
        for (; t >= tb; --t) {
            const float xt = xbuf[t - tb];
            v2f a0 = (v2f){0.0f, 0.0f};
            v2f a1 = (v2f){0.0f, 0.0f};
#pragma unroll
            for (int q = 0; q < 16; ++q) {
                a0 = __builtin_elementwise_fma(w0[q], h2[q], a0);
                a1 = __builtin_elementwise_fma(w1[q], h2[q], a1);
            }
            const float g0 = (a0.x + a0.y) + fmaf(wi0, xt, bi0);
            const float g1 = (a1.x + a1.y) + fmaf(wi1, xt, bi1);
            // acc0 is sigmoid for all lanes: i (lower) / f (upper)
            const float s0 = frcp(1.0f + fexp2(g0 * -1.4426950408889634f));
            // acc1: tanh(g) lower / sigmoid(o) upper
            const float s1 = frcp(1.0f + fexp2(g1 * kmul));
            const float v1 = fmaf(amul, s1, badd);
            // lower lanes need f (partner s0) and o (partner v1)
            const float fg = __shfl_xor(s0, 32);
            const float og = __shfl_xor(v1, 32);
            // lower lanes: i=s0, g=v1 ; c,h only meaningful there (upper lanes junk)
            c = fmaf(fg, c, s0 * v1);
            const float hn = og * ftanh(c);
            hbuf[lane] = hn;           // upper 32 write to pad region, never read
            __syncthreads();
            const v4f* hp = reinterpret_cast<const v4f*>(hbuf);
#pragma unroll
            for (int q = 0; q < 8; ++q) {
                v4f r = hp[q];                 // same-address broadcast read
                h2[2 * q]     = r.xy;
                h2[2 * q + 1] = r.zw;
            }
        }
    }

    // ---- head: out[b] = sigmoid( sum_r fc2_w[r]*elu(fc_w[r]@h + fc_b[r]) + fc2_b ) ----
    float a = fc_b[lane];
    {
        const v2f* fp = reinterpret_cast<const v2f*>(fc_w + lane * 32);
        v2f fa = (v2f){0.0f, 0.0f};
#pragma unroll
        for (int q = 0; q < 16; ++q) fa = __builtin_elementwise_fma(fp[q], h2[q], fa);
        a += fa.x + fa.y;
    }
    float partial = felu(a) * fc2_w[lane];
#pragma unroll
    for (int m = 32; m >= 1; m >>= 1) partial += __shfl_xor(partial, m, 64);
    if (lane == 0) out[b] = fsigmoid(partial + fc2_b[0]);
}

extern "C" void kernel_launch(void* const* d_in, const int* in_sizes, int n_in,
                              void* d_out, int out_size, void* d_ws, size_t ws_size,
                              hipStream_t stream) {
    const float* x       = (const float*)d_in[0];
    const int*   lengths = (const int*)d_in[1];
    const float* w_ih    = (const float*)d_in[2];
    const float* w_hh    = (const float*)d_in[3];
    const float* b_ih    = (const float*)d_in[4];
    const float* b_hh    = (const float*)d_in[5];
    const float* fc_w    = (const float*)d_in[6];
    const float* fc_b    = (const float*)d_in[7];
    const float* fc2_w   = (const float*)d_in[8];
    const float* fc2_b   = (const float*)d_in[9];
    float* out = (float*)d_out;

    int* perm = nullptr;
    if (ws_size >= (size_t)BB * sizeof(int)) {
        perm = (int*)d_ws;
        hipLaunchKernelGGL(sort_by_len_kernel, dim3(1), dim3(256), 0, stream, lengths, perm);
    }
    hipLaunchKernelGGL(lstm_kernel, dim3(BB), dim3(64), 0, stream,
                       x, lengths, w_ih, w_hh, b_ih, b_hh,
                       fc_w, fc_b, fc2_w, fc2_b, out, perm);
}

// Round 4
// 691.164 us; speedup vs baseline: 1.0669x; 1.0669x over previous
//
#include <hip/hip_runtime.h>
#include <hip/hip_bf16.h>

constexpr int BB = 4096;   // batch
constexpr int TT = 2048;   // time
constexpr int HH = 32;     // hidden

typedef float v2f __attribute__((ext_vector_type(2)));
typedef float v4f __attribute__((ext_vector_type(4)));

// ---------- fast math (v_exp_f32 / v_rcp_f32) ----------
__device__ __forceinline__ float fexp2(float x) { return __builtin_amdgcn_exp2f(x); }
__device__ __forceinline__ float frcp(float x)  { return __builtin_amdgcn_rcpf(x); }
__device__ __forceinline__ float fsigmoid(float x) {
    return frcp(1.0f + fexp2(x * -1.4426950408889634f));
}
__device__ __forceinline__ float felu(float x) {
    return x > 0.0f ? x : (fexp2(x * 1.4426950408889634f) - 1.0f);
}

// ---------- kernel 1: counting sort of batch indices by length, descending ----------
__global__ void sort_by_len_kernel(const int* __restrict__ lengths, int* __restrict__ perm) {
    __shared__ int hist[TT];     // key = TT - len  in [0, TT-1]
    __shared__ int csum[256];
    const int tid = threadIdx.x;
    for (int i = tid; i < TT; i += 256) hist[i] = 0;
    __syncthreads();
    for (int i = tid; i < BB; i += 256) atomicAdd(&hist[TT - lengths[i]], 1);
    __syncthreads();
    const int base = tid * 8;
    int loc[8];
    int s = 0;
#pragma unroll
    for (int j = 0; j < 8; ++j) { loc[j] = hist[base + j]; s += loc[j]; }
    csum[tid] = s;
    __syncthreads();
    for (int off = 1; off < 256; off <<= 1) {
        int v = (tid >= off) ? csum[tid - off] : 0;
        __syncthreads();
        csum[tid] += v;
        __syncthreads();
    }
    int run = csum[tid] - s;
#pragma unroll
    for (int j = 0; j < 8; ++j) { int t = loc[j]; hist[base + j] = run; run += t; }
    __syncthreads();
    for (int i = tid; i < BB; i += 256) {
        int pos = atomicAdd(&hist[TT - lengths[i]], 1);
        perm[pos] = i;
    }
}

// ---------- kernel 2: backward LSTM + MLP head ----------
// 1 wave per block, 1 batch element per wave. Lane owns gate rows:
//   r0 = lane        (rows 0..63   = i then f)   -- both sigmoid
//   r1 = lane + 64   (rows 64..127 = g then o)   -- tanh (lower) / sigmoid (upper)
// Rows are PRE-SCALED by -log2e (sigmoid) / -2log2e (tanh) so activations are
// exp2+add+rcp with no input multiply.
// anti-remat pin: R2/R3 showed the RA rematerializes invariant weight loads
// into the K-loop (VGPR_Count 60/68, ~150 instr/step). The empty asm makes
// the loaded values opaque, forcing true register residency.
__global__ __attribute__((amdgpu_flat_work_group_size(64, 64), amdgpu_waves_per_eu(2, 3)))
void lstm_kernel(const float* __restrict__ x, const int* __restrict__ lengths,
                 const float* __restrict__ w_ih, const float* __restrict__ w_hh,
                 const float* __restrict__ b_ih, const float* __restrict__ b_hh,
                 const float* __restrict__ fc_w, const float* __restrict__ fc_b,
                 const float* __restrict__ fc2_w, const float* __restrict__ fc2_b,
                 float* __restrict__ out, const int* __restrict__ perm) {
    __shared__ __align__(16) float hbuf[64];   // only [0..31] read; [32..63] = junk pad
    __shared__ float xbuf[64];

    const int lane = threadIdx.x;       // 0..63
    const int b = perm ? perm[blockIdx.x] : blockIdx.x;
    const int L = lengths[b];

    const int r0 = lane;        // i (lane<32) / f (lane>=32) row
    const int r1 = lane + 64;   // g (lane<32) / o (lane>=32) row

    const bool  lower  = lane < 32;
    const float NL2E   = -1.4426950408889634f;           // -log2(e)
    const float scale0 = NL2E;                           // i/f: sigmoid
    const float scale1 = lower ? 2.0f * NL2E : NL2E;     // g: tanh, o: sigmoid
    const float amul   = lower ? 2.0f : 1.0f;
    const float badd   = lower ? -1.0f : 0.0f;

    // per-lane pre-scaled weights in registers
    v2f w0[16], w1[16];
    {
        const v2f* p0 = reinterpret_cast<const v2f*>(w_hh + r0 * 32);
        const v2f* p1 = reinterpret_cast<const v2f*>(w_hh + r1 * 32);
#pragma unroll
        for (int q = 0; q < 16; ++q) {
            w0[q] = p0[q] * scale0;
            w1[q] = p1[q] * scale1;
        }
    }
    float wi0 = w_ih[r0] * scale0;
    float wi1 = w_ih[r1] * scale1;
    float bi0 = (b_ih[r0] + b_hh[r0]) * scale0;
    float bi1 = (b_ih[r1] + b_hh[r1]) * scale1;

    // ---- anti-remat pin: values become opaque, loads cannot be re-sunk ----
#pragma unroll
    for (int q = 0; q < 16; ++q) {
        asm volatile("" : "+v"(w0[q]), "+v"(w1[q]));
    }
    asm volatile("" : "+v"(wi0), "+v"(wi1), "+v"(bi0), "+v"(bi1));

    v2f h2[16];
#pragma unroll
    for (int q = 0; q < 16; ++q) h2[q] = (v2f){0.0f, 0.0f};
    float c = 0.0f;
    const float* xb = x + (size_t)b * TT;

    int t = L - 1;
    while (t >= 0) {
        const int tb = t & ~63;
        __syncthreads();
        xbuf[lane] = xb[tb + lane];    // tb+63 <= 2047 always in-bounds
        __syncthreads();
        for (; t >= tb; --t) {
            const float xt = xbuf[t - tb];
            v2f a0 = (v2f){fmaf(wi0, xt, bi0), 0.0f};
            v2f a1 = (v2f){fmaf(wi1, xt, bi1), 0.0f};
#pragma unroll
            for (int q = 0; q < 16; ++q) {
                a0 = __builtin_elementwise_fma(w0[q], h2[q], a0);
                a1 = __builtin_elementwise_fma(w1[q], h2[q], a1);
            }
            const float g0 = a0.x + a0.y;     // pre-scaled gate inputs
            const float g1 = a1.x + a1.y;
            const float s0 = frcp(1.0f + fexp2(g0));           // sigmoid(i/f)
            const float s1 = frcp(1.0f + fexp2(g1));
            const float v1 = fmaf(amul, s1, badd);             // tanh(g) / sigmoid(o)
            const float fg = __shfl_xor(s0, 32);
            const float og = __shfl_xor(v1, 32);
            c = fmaf(fg, c, s0 * v1);
            // tanh(c) = 1 - 2*rcp(1+exp2(2*log2e*c))
            const float tc = 1.0f - 2.0f * frcp(1.0f + fexp2(c * 2.8853900817779268f));
            const float hn = og * tc;
            hbuf[lane] = hn;           // upper 32 write to pad region, never read
            __syncthreads();
            const v4f* hp = reinterpret_cast<const v4f*>(hbuf);
#pragma unroll
            for (int q = 0; q < 8; ++q) {
                v4f r = hp[q];                 // same-address broadcast read
                h2[2 * q]     = r.xy;
                h2[2 * q + 1] = r.zw;
            }
        }
    }

    // ---- head: out[b] = sigmoid( sum_r fc2_w[r]*elu(fc_w[r]@h + fc_b[r]) + fc2_b ) ----
    float a = fc_b[lane];
    {
        const v2f* fp = reinterpret_cast<const v2f*>(fc_w + lane * 32);
        v2f fa = (v2f){0.0f, 0.0f};
#pragma unroll
        for (int q = 0; q < 16; ++q) fa = __builtin_elementwise_fma(fp[q], h2[q], fa);
        a += fa.x + fa.y;
    }
    float partial = felu(a) * fc2_w[lane];
#pragma unroll
    for (int m = 32; m >= 1; m >>= 1) partial += __shfl_xor(partial, m, 64);
    if (lane == 0) out[b] = fsigmoid(partial + fc2_b[0]);
}

extern "C" void kernel_launch(void* const* d_in, const int* in_sizes, int n_in,
                              void* d_out, int out_size, void* d_ws, size_t ws_size,
                              hipStream_t stream) {
    const float* x       = (const float*)d_in[0];
    const int*   lengths = (const int*)d_in[1];
    const float* w_ih    = (const float*)d_in[2];
    const float* w_hh    = (const float*)d_in[3];
    const float* b_ih    = (const float*)d_in[4];
    const float* b_hh    = (const float*)d_in[5];
    const float* fc_w    = (const float*)d_in[6];
    const float* fc_b    = (const float*)d_in[7];
    const float* fc2_w   = (const float*)d_in[8];
    const float* fc2_b   = (const float*)d_in[9];
    float* out = (float*)d_out;

    int* perm = nullptr;
    if (ws_size >= (size_t)BB * sizeof(int)) {
        perm = (int*)d_ws;
        hipLaunchKernelGGL(sort_by_len_kernel, dim3(1), dim3(256), 0, stream, lengths, perm);
    }
    hipLaunchKernelGGL(lstm_kernel, dim3(BB), dim3(64), 0, stream,
                       x, lengths, w_ih, w_hh, b_ih, b_hh,
                       fc_w, fc_b, fc2_w, fc2_b, out, perm);
}

// Round 5
// 643.766 us; speedup vs baseline: 1.1455x; 1.0736x over previous
//
#include <hip/hip_runtime.h>
#include <hip/hip_bf16.h>

constexpr int BB = 4096;   // batch
constexpr int TT = 2048;   // time
constexpr int HH = 32;     // hidden

typedef float v2f __attribute__((ext_vector_type(2)));
typedef float v4f __attribute__((ext_vector_type(4)));
typedef _Float16 v2h __attribute__((ext_vector_type(2)));
typedef _Float16 v8h __attribute__((ext_vector_type(8)));

// ---------- fast math (v_exp_f32 / v_rcp_f32) ----------
__device__ __forceinline__ float fexp2(float x) { return __builtin_amdgcn_exp2f(x); }
__device__ __forceinline__ float frcp(float x)  { return __builtin_amdgcn_rcpf(x); }
__device__ __forceinline__ float fsigmoid(float x) {
    return frcp(1.0f + fexp2(x * -1.4426950408889634f));
}
__device__ __forceinline__ float felu(float x) {
    return x > 0.0f ? x : (fexp2(x * 1.4426950408889634f) - 1.0f);
}

// ---------- kernel 1: counting sort of batch indices by length, descending ----------
__global__ void sort_by_len_kernel(const int* __restrict__ lengths, int* __restrict__ perm) {
    __shared__ int hist[TT];     // key = TT - len  in [0, TT-1]
    __shared__ int csum[256];
    const int tid = threadIdx.x;
    for (int i = tid; i < TT; i += 256) hist[i] = 0;
    __syncthreads();
    for (int i = tid; i < BB; i += 256) atomicAdd(&hist[TT - lengths[i]], 1);
    __syncthreads();
    const int base = tid * 8;
    int loc[8];
    int s = 0;
#pragma unroll
    for (int j = 0; j < 8; ++j) { loc[j] = hist[base + j]; s += loc[j]; }
    csum[tid] = s;
    __syncthreads();
    for (int off = 1; off < 256; off <<= 1) {
        int v = (tid >= off) ? csum[tid - off] : 0;
        __syncthreads();
        csum[tid] += v;
        __syncthreads();
    }
    int run = csum[tid] - s;
#pragma unroll
    for (int j = 0; j < 8; ++j) { int t = loc[j]; hist[base + j] = run; run += t; }
    __syncthreads();
    for (int i = tid; i < BB; i += 256) {
        int pos = atomicAdd(&hist[TT - lengths[i]], 1);
        perm[pos] = i;
    }
}

// ---------- kernel 2: backward LSTM + MLP head (f16 dot2 edition) ----------
// 1 wave per block, 1 batch element per wave. NO __syncthreads anywhere
// (single-wave workgroup => LDS is wave-coherent, lgkmcnt only).
// Gate row ownership (unit n = lane&31):
//   lower lane n    : r0 = n      (i), r1 = 64+n (g)  -> computes ig = sig(i)*tanh(g)
//   upper lane 32+n : r0 = 32+n   (f), r1 = 96+n (o)  -> owns c, computes h
// One __shfl_xor(ig, 32) per step moves ig to the c-owner. Weights are f16
// pairs (32 VGPRs total) consumed by v_dot2_f32_f16 (2 MAC/lane/instr, f32 acc).
// Rows pre-scaled by -log2e (sigmoid) / -2log2e (tanh): act = rcp(1+exp2(g)).
__global__ __attribute__((amdgpu_flat_work_group_size(64, 64), amdgpu_waves_per_eu(1, 4)))
void lstm_kernel(const float* __restrict__ x, const int* __restrict__ lengths,
                 const float* __restrict__ w_ih, const float* __restrict__ w_hh,
                 const float* __restrict__ b_ih, const float* __restrict__ b_hh,
                 const float* __restrict__ fc_w, const float* __restrict__ fc_b,
                 const float* __restrict__ fc2_w, const float* __restrict__ fc2_b,
                 float* __restrict__ out, const int* __restrict__ perm) {
    __shared__ __align__(16) _Float16 hs[64];  // [0..31] junk from lower lanes; [32..63] = h
    __shared__ float xbuf[64];

    const int lane = threadIdx.x;       // 0..63
    const int b = perm ? perm[blockIdx.x] : blockIdx.x;
    const int L = lengths[b];

    const int r0 = lane;        // i (lower) / f (upper)
    const int r1 = lane + 64;   // g (lower) / o (upper)

    const bool  lower  = lane < 32;
    const float NL2E   = -1.4426950408889634f;
    const float scale0 = NL2E;                           // i/f: sigmoid
    const float scale1 = lower ? 2.0f * NL2E : NL2E;     // g: tanh, o: sigmoid
    const float amul   = lower ? 2.0f : 1.0f;
    const float badd   = lower ? -1.0f : 0.0f;

    // per-lane pre-scaled f16 weights in registers (16+16 VGPRs)
    v2h w0[16], w1[16];
    {
        const v2f* p0 = reinterpret_cast<const v2f*>(w_hh + r0 * 32);
        const v2f* p1 = reinterpret_cast<const v2f*>(w_hh + r1 * 32);
#pragma unroll
        for (int q = 0; q < 16; ++q) {
            v2f a = p0[q]; v2f bq = p1[q];
            w0[q] = (v2h){(_Float16)(a.x * scale0), (_Float16)(a.y * scale0)};
            w1[q] = (v2h){(_Float16)(bq.x * scale1), (_Float16)(bq.y * scale1)};
        }
    }
    float wi0 = w_ih[r0] * scale0;
    float wi1 = w_ih[r1] * scale1;
    float bi0 = (b_ih[r0] + b_hh[r0]) * scale0;
    float bi1 = (b_ih[r1] + b_hh[r1]) * scale1;

    // anti-remat pin (cheap insurance; pressure is low enough to stay in VGPRs)
#pragma unroll
    for (int q = 0; q < 16; ++q) {
        asm volatile("" : "+v"(w0[q]), "+v"(w1[q]));
    }

    v8h hr[4];
#pragma unroll
    for (int q = 0; q < 4; ++q) hr[q] = (v8h)(_Float16)0.0f;
    float c = 0.0f;
    const float* xb = x + (size_t)b * TT;

    int t = L - 1;
    while (t >= 0) {
        const int tb = t & ~63;
        xbuf[lane] = xb[tb + lane];    // wave-local staging, no barrier needed
        for (; t >= tb; --t) {
            const float xt = xbuf[t - tb];
            float a0  = fmaf(wi0, xt, bi0);
            float a1  = fmaf(wi1, xt, bi1);
            float a0b = 0.0f, a1b = 0.0f;
#pragma unroll
            for (int q = 0; q < 4; ++q) {
                const v8h hh = hr[q];
                const v2h p01 = __builtin_shufflevector(hh, hh, 0, 1);
                const v2h p23 = __builtin_shufflevector(hh, hh, 2, 3);
                const v2h p45 = __builtin_shufflevector(hh, hh, 4, 5);
                const v2h p67 = __builtin_shufflevector(hh, hh, 6, 7);
                a0  = __builtin_amdgcn_fdot2(w0[4*q+0], p01, a0,  false);
                a0b = __builtin_amdgcn_fdot2(w0[4*q+1], p23, a0b, false);
                a0  = __builtin_amdgcn_fdot2(w0[4*q+2], p45, a0,  false);
                a0b = __builtin_amdgcn_fdot2(w0[4*q+3], p67, a0b, false);
                a1  = __builtin_amdgcn_fdot2(w1[4*q+0], p01, a1,  false);
                a1b = __builtin_amdgcn_fdot2(w1[4*q+1], p23, a1b, false);
                a1  = __builtin_amdgcn_fdot2(w1[4*q+2], p45, a1,  false);
                a1b = __builtin_amdgcn_fdot2(w1[4*q+3], p67, a1b, false);
            }
            const float g0 = a0 + a0b;     // pre-scaled gate inputs
            const float g1 = a1 + a1b;
            const float s0 = frcp(1.0f + fexp2(g0));   // sig(i) / sig(f)
            const float s1 = frcp(1.0f + fexp2(g1));
            const float v1 = fmaf(amul, s1, badd);     // tanh(g) / sig(o)
            const float ig = s0 * v1;                  // lower: i*g (upper: junk)
            const float igx = __shfl_xor(ig, 32);
            // upper lanes own c:  c = f*c + i*g
            c = fmaf(s0, c, igx);
            const float tc = 1.0f - 2.0f * frcp(1.0f + fexp2(c * 2.8853900817779268f));
            const float hn = v1 * tc;                  // upper: sig(o)*tanh(c)
            hs[lane] = (_Float16)hn;                   // real h lands at hs[32..63]
            const v8h* hp = reinterpret_cast<const v8h*>(hs + 32);
#pragma unroll
            for (int q = 0; q < 4; ++q) hr[q] = hp[q]; // broadcast reads
        }
    }

    // ---- head: out[b] = sigmoid( sum_r fc2_w[r]*elu(fc_w[r]@h + fc_b[r]) + fc2_b ) ----
    float hf[32];
#pragma unroll
    for (int q = 0; q < 4; ++q) {
        const v8h hh = hr[q];
#pragma unroll
        for (int j = 0; j < 8; ++j) hf[8 * q + j] = (float)hh[j];
    }
    float a = fc_b[lane];
    {
        const v4f* fp = reinterpret_cast<const v4f*>(fc_w + lane * 32);
#pragma unroll
        for (int q = 0; q < 8; ++q) {
            const v4f f = fp[q];
            a = fmaf(f.x, hf[4 * q + 0], a);
            a = fmaf(f.y, hf[4 * q + 1], a);
            a = fmaf(f.z, hf[4 * q + 2], a);
            a = fmaf(f.w, hf[4 * q + 3], a);
        }
    }
    float partial = felu(a) * fc2_w[lane];
#pragma unroll
    for (int m = 32; m >= 1; m >>= 1) partial += __shfl_xor(partial, m, 64);
    if (lane == 0) out[b] = fsigmoid(partial + fc2_b[0]);
}

extern "C" void kernel_launch(void* const* d_in, const int* in_sizes, int n_in,
                              void* d_out, int out_size, void* d_ws, size_t ws_size,
                              hipStream_t stream) {
    const float* x       = (const float*)d_in[0];
    const int*   lengths = (const int*)d_in[1];
    const float* w_ih    = (const float*)d_in[2];
    const float* w_hh    = (const float*)d_in[3];
    const float* b_ih    = (const float*)d_in[4];
    const float* b_hh    = (const float*)d_in[5];
    const float* fc_w    = (const float*)d_in[6];
    const float* fc_b    = (const float*)d_in[7];
    const float* fc2_w   = (const float*)d_in[8];
    const float* fc2_b   = (const float*)d_in[9];
    float* out = (float*)d_out;

    int* perm = nullptr;
    if (ws_size >= (size_t)BB * sizeof(int)) {
        perm = (int*)d_ws;
        hipLaunchKernelGGL(sort_by_len_kernel, dim3(1), dim3(256), 0, stream, lengths, perm);
    }
    hipLaunchKernelGGL(lstm_kernel, dim3(BB), dim3(64), 0, stream,
                       x, lengths, w_ih, w_hh, b_ih, b_hh,
                       fc_w, fc_b, fc2_w, fc2_b, out, perm);
}